// Round 17
// baseline (114.177 us; speedup 1.0000x reference)
//
#include <hip/hip_runtime.h>

#define NV 2052
#define KD 512
#define RTOT 2564
#define KTOT 256
#define JTOT 8192

typedef __attribute__((ext_vector_type(8))) short short8v;
typedef __attribute__((ext_vector_type(4))) float f32x4;
typedef unsigned short ushort_t;

// ws float offsets
#define OFF_AF   0u          // fp32 M1 [512][128]
#define OFF_ABF  65536u      // bf16 A' [2688][256]  (hi|lo)
#define OFF_BBF  409600u     // bf16 B' [8192][128]  (hi only)
#define OFF_YBF  1458176u    // bf16 Y  [256][8192]
#define OFF_PG   2506752u    // fp32 Gram partials [32][4][128][128]
#define OFF_PM1  6701056u    // fp32 m1 partials [16][512][128]
#define OFF_A    7749632u
#define OFF_X    7766016u
#define OFF_XW   7782400u    // fp32 XW [128][64]

#define SREC_OFF 4194304u
#define AAUG_OFF 21004288u

#define GLOAD16(g, l) __builtin_amdgcn_global_load_lds( \
    (const __attribute__((address_space(1))) unsigned int*)(g), \
    (__attribute__((address_space(3))) unsigned int*)(l), 16, 0, 0)

__device__ __forceinline__ float dct_val(int k, int v) {
    if (k == 0) return 1.0f / sqrtf(2052.0f);
    int m = (2 * v + 1) * k;
    int r = m % 8208;                       // exact arg reduction mod 2*pi
    float ang = (float)((double)r * (3.14159265358979323846 / 4104.0));
    return sqrtf(2.0f / 2052.0f) * cosf(ang);
}

__device__ __forceinline__ void bf16split(float x, ushort_t& hi, ushort_t& lo) {
    unsigned xb = __float_as_uint(x);
    hi = (ushort_t)(xb >> 16);
    float r = x - __uint_as_float((unsigned)hi << 16);
    lo = (ushort_t)(__float_as_uint(r) >> 16);
}

__device__ __forceinline__ ushort_t bf16rn(float x) {
    unsigned xb = __float_as_uint(x);
    return (ushort_t)((xb + 0x7fffu + ((xb >> 16) & 1u)) >> 16);
}

// ---------- shared GEMM tile body: C-tile (r0, jt) ----------
__device__ __forceinline__ void gemm_tile(ushort_t* SM, const ushort_t* __restrict__ Abf,
                                          const ushort_t* __restrict__ Bbf, float* __restrict__ out,
                                          int r0, int jt, int tid) {
    const int wave = tid >> 6;
    const int lane = tid & 63;
    const int wr = wave >> 1, wc = wave & 1;
    const int l15 = lane & 15;
    const int lhi = lane >> 4;
    const int j0 = jt * 128;
    ushort_t* AlHi = SM;
    ushort_t* AlLo = SM + 8192;
    ushort_t* Bl   = SM + 16384;
    f32x4 acc[4][4];
    #pragma unroll
    for (int i = 0; i < 4; ++i)
        #pragma unroll
        for (int j = 0; j < 4; ++j)
            acc[i][j] = (f32x4){0.f, 0.f, 0.f, 0.f};
    for (int kc = 0; kc < 128; kc += 64) {
        __syncthreads();
        #pragma unroll
        for (int i = 0; i < 4; ++i) {
            int elt = (wave * 4 + i) * 64 + lane;   // 16B-chunk id 0..1023
            int m = elt >> 3;
            int sc = (elt & 7) ^ (m & 7);
            GLOAD16(Abf + (size_t)(r0 + m) * KTOT + kc + sc * 8,       &AlHi[(wave * 4 + i) * 512]);
            GLOAD16(Abf + (size_t)(r0 + m) * KTOT + 128 + kc + sc * 8, &AlLo[(wave * 4 + i) * 512]);
            GLOAD16(Bbf + (size_t)(j0 + m) * 128 + kc + sc * 8,        &Bl[(wave * 4 + i) * 512]);
        }
        asm volatile("s_waitcnt vmcnt(0)" ::: "memory");
        __syncthreads();
        #pragma unroll
        for (int kk = 0; kk < 2; ++kk) {
            short8v ah[4], al[4], bv[4];
            #pragma unroll
            for (int mi = 0; mi < 4; ++mi) {
                int m = wr * 64 + mi * 16 + l15;
                int ch = (kk * 4 + lhi) ^ (m & 7);
                ah[mi] = *(const short8v*)&AlHi[m * 64 + ch * 8];
                al[mi] = *(const short8v*)&AlLo[m * 64 + ch * 8];
            }
            #pragma unroll
            for (int ni = 0; ni < 4; ++ni) {
                int n = wc * 64 + ni * 16 + l15;
                int ch = (kk * 4 + lhi) ^ (n & 7);
                bv[ni] = *(const short8v*)&Bl[n * 64 + ch * 8];
            }
            #pragma unroll
            for (int mi = 0; mi < 4; ++mi)
                #pragma unroll
                for (int ni = 0; ni < 4; ++ni)
                    acc[mi][ni] = __builtin_amdgcn_mfma_f32_16x16x32_bf16(ah[mi], bv[ni], acc[mi][ni], 0, 0, 0);
            #pragma unroll
            for (int mi = 0; mi < 4; ++mi)
                #pragma unroll
                for (int ni = 0; ni < 4; ++ni)
                    acc[mi][ni] = __builtin_amdgcn_mfma_f32_16x16x32_bf16(al[mi], bv[ni], acc[mi][ni], 0, 0, 0);
        }
    }
    // epilogue: LDS transpose -> coalesced float4 stores (two 64-col halves)
    float* SMf = (float*)SM;
    const unsigned bb = (unsigned)jt;
    #pragma unroll
    for (int hhalf = 0; hhalf < 2; ++hhalf) {
        __syncthreads();
        if (wc == hhalf) {
            #pragma unroll
            for (int mi = 0; mi < 4; ++mi)
                #pragma unroll
                for (int ni = 0; ni < 4; ++ni)
                    #pragma unroll
                    for (int reg = 0; reg < 4; ++reg) {
                        int rl = wr * 64 + mi * 16 + lhi * 4 + reg;
                        int cl = ni * 16 + l15;
                        SMf[rl * 68 + cl] = acc[mi][ni][reg];
                    }
        }
        __syncthreads();
        int rl = tid >> 1;
        int cs = (tid & 1) * 32;
        int r = r0 + rl;
        if (r < RTOT) {
            unsigned base;
            if (r < KD) base = bb * 65536u + (unsigned)r * 128u;
            else        base = SREC_OFF + bb * 262656u + (unsigned)(r - KD) * 128u;
            base += hhalf * 64 + cs;
            const float* src = &SMf[rl * 68 + cs];
            float* dst = out + base;
            #pragma unroll
            for (int q = 0; q < 8; ++q)
                *(float4*)(dst + q * 4) = *(const float4*)(src + q * 4);
        }
    }
}

// ========== FRONT: blocks 0..1023 = m1 partials; 1024..5119 = hilbert (2 rows/blk) ==========
__global__ __launch_bounds__(256) void k_front(const float* __restrict__ LF, const float* __restrict__ z,
                                               float* __restrict__ Pm1,
                                               ushort_t* __restrict__ Ybf, ushort_t* __restrict__ Bbf) {
    __shared__ float sh[8][132];
    const int tid = threadIdx.x;
    const int bid = blockIdx.x;
    if (bid < 1024) {
        const int t = tid & 127;
        const int kk = tid >> 7;       // 0/1
        const int k0 = (bid & 63) * 8;
        const int vch = bid >> 6;
        const int v0 = vch * 128;
        const int nv = (vch == 15) ? 132 : 128;
        for (int p = tid; p < 1056; p += 256) {
            int rr = p / 132, cc = p - rr * 132;
            sh[rr][cc] = dct_val(k0 + rr, v0 + cc);
        }
        __syncthreads();
        const float* lf = LF + (size_t)v0 * 128 + t;
        float a0 = 0.f, a1 = 0.f, a2 = 0.f, a3 = 0.f;
        for (int vi = 0; vi + 2 <= nv; vi += 2) {
            float l0 = lf[vi * 128], l1 = lf[vi * 128 + 128];
            a0 += sh[kk + 0][vi] * l0; a1 += sh[kk + 2][vi] * l0;
            a2 += sh[kk + 4][vi] * l0; a3 += sh[kk + 6][vi] * l0;
            a0 += sh[kk + 0][vi + 1] * l1; a1 += sh[kk + 2][vi + 1] * l1;
            a2 += sh[kk + 4][vi + 1] * l1; a3 += sh[kk + 6][vi + 1] * l1;
        }
        float* P = Pm1 + (size_t)vch * 65536;
        P[(k0 + kk + 0) * 128 + t] = a0;
        P[(k0 + kk + 2) * 128 + t] = a1;
        P[(k0 + kk + 4) * 128 + t] = a2;
        P[(k0 + kk + 6) * 128 + t] = a3;
    } else {
        const int t = tid & 127;
        const int rr = tid >> 7;
        const int rid = (bid - 1024) * 2 + rr;   // b*128+i
        const int b = rid >> 7, i = rid & 127;
        sh[rr][t] = z[(size_t)rid * 128 + t];
        if (tid < 128) {
            float hv = 0.f;
            if (t & 1) {
                float ang = 3.14159265358979323846f * (float)t * (1.0f / 128.0f);
                hv = (cosf(ang) / sinf(ang)) * (1.0f / 64.0f);
            }
            sh[2][t] = hv;
        }
        __syncthreads();
        float acc = 0.f;
        #pragma unroll 8
        for (int q = 0; q < 64; ++q) {
            int d = 2 * q + 1;
            acc += sh[2][d] * sh[rr][(t - d) & 127];
        }
        float zv = sh[rr][t];
        float inv = rsqrtf(zv * zv + acc * acc);
        Ybf[(size_t)i * JTOT + b * 128 + t] = bf16rn(zv * inv);
        Ybf[(size_t)(128 + i) * JTOT + b * 128 + t] = bf16rn(acc * inv);
        Bbf[(size_t)rid * 128 + t] = (ushort_t)(__float_as_uint(zv) >> 16);
    }
}

// ========== M1RED: 0..255 reduce -> AF+Abf; 256..319 X; 320..447 Gram ==========
__global__ __launch_bounds__(256) void k_m1red(const float* __restrict__ Pm1, const float* __restrict__ z,
                                               float* __restrict__ AF, ushort_t* __restrict__ Abf,
                                               float* __restrict__ X,
                                               const ushort_t* __restrict__ Ybf, float* __restrict__ Pg) {
    __shared__ ushort_t SMg[16384];   // 32 KB (gram only)
    const int tid = threadIdx.x;
    const int bid = blockIdx.x;
    if (bid < 256) {
        int id = bid * 256 + tid;  // 65536
        float s = 0.f;
        #pragma unroll
        for (int p = 0; p < 16; ++p) s += Pm1[p * 65536 + id];
        AF[id] = s;
        int rid = id >> 7, t = id & 127;
        ushort_t hi, lo; bf16split(s, hi, lo);
        ushort_t* row = Abf + (size_t)rid * KTOT;
        row[t] = hi; row[128 + t] = lo;
    } else if (bid < 320) {
        int id = (bid - 256) * 256 + tid;  // 16384
        float s0 = 0.f, s1 = 0.f, s2 = 0.f, s3 = 0.f;
        #pragma unroll 4
        for (int b = 0; b < 64; b += 4) {
            s0 += z[(size_t)(b + 0) * 16384 + id];
            s1 += z[(size_t)(b + 1) * 16384 + id];
            s2 += z[(size_t)(b + 2) * 16384 + id];
            s3 += z[(size_t)(b + 3) * 16384 + id];
        }
        X[id] = ((s0 + s1) + (s2 + s3)) * (1.0f / 64.0f);
    } else {
        // ---------- Gram partials: 128 blocks = 32 K-chunks x 4 quadrants ----------
        const int g = bid - 320;
        const int j0 = (g & 1) * 128;
        const int i0 = ((g >> 1) & 1) * 128;
        const int sk = g >> 2;               // 0..31
        const int kc0 = sk * 256;
        const int wave = tid >> 6;
        const int lane = tid & 63;
        const int wr = wave >> 1, wc = wave & 1;
        const int l15 = lane & 15;
        const int lhi = lane >> 4;
        ushort_t* Al = SMg;
        ushort_t* Bl = SMg + 8192;
        f32x4 acc[4][4];
        #pragma unroll
        for (int i = 0; i < 4; ++i)
            #pragma unroll
            for (int j = 0; j < 4; ++j)
                acc[i][j] = (f32x4){0.f, 0.f, 0.f, 0.f};
        for (int kc = kc0; kc < kc0 + 256; kc += 64) {
            __syncthreads();
            #pragma unroll
            for (int i = 0; i < 4; ++i) {
                int elt = (wave * 4 + i) * 64 + lane;
                int m = elt >> 3;
                int sc = (elt & 7) ^ (m & 7);
                GLOAD16(Ybf + (size_t)(i0 + m) * JTOT + kc + sc * 8, &Al[(wave * 4 + i) * 512]);
                GLOAD16(Ybf + (size_t)(j0 + m) * JTOT + kc + sc * 8, &Bl[(wave * 4 + i) * 512]);
            }
            asm volatile("s_waitcnt vmcnt(0)" ::: "memory");
            __syncthreads();
            #pragma unroll
            for (int kk = 0; kk < 2; ++kk) {
                short8v av[4], bv[4];
                #pragma unroll
                for (int mi = 0; mi < 4; ++mi) {
                    int m = wr * 64 + mi * 16 + l15;
                    int ch = (kk * 4 + lhi) ^ (m & 7);
                    av[mi] = *(const short8v*)&Al[m * 64 + ch * 8];
                }
                #pragma unroll
                for (int ni = 0; ni < 4; ++ni) {
                    int n = wc * 64 + ni * 16 + l15;
                    int ch = (kk * 4 + lhi) ^ (n & 7);
                    bv[ni] = *(const short8v*)&Bl[n * 64 + ch * 8];
                }
                #pragma unroll
                for (int mi = 0; mi < 4; ++mi)
                    #pragma unroll
                    for (int ni = 0; ni < 4; ++ni)
                        acc[mi][ni] = __builtin_amdgcn_mfma_f32_16x16x32_bf16(av[mi], bv[ni], acc[mi][ni], 0, 0, 0);
            }
        }
        const int q = ((g >> 1) & 1) * 2 + (g & 1);
        float* P = Pg + (size_t)(sk * 4 + q) * 16384;
        #pragma unroll
        for (int mi = 0; mi < 4; ++mi)
            #pragma unroll
            for (int reg = 0; reg < 4; ++reg) {
                int rl = wr * 64 + mi * 16 + lhi * 4 + reg;
                #pragma unroll
                for (int ni = 0; ni < 4; ++ni) {
                    int cl = wc * 64 + ni * 16 + l15;
                    P[rl * 128 + cl] = acc[mi][ni][reg];
                }
            }
    }
}

// ========== M2+: 0..128 M2 (16v/blk); 129..384 GEMM r0..3; 385..448 plv; 449..480 XW ==========
__global__ __launch_bounds__(256) void k_m2(const float* __restrict__ M1, ushort_t* __restrict__ Abf,
                                            const ushort_t* __restrict__ Bbf, float* __restrict__ out,
                                            const float* __restrict__ Pg, const float* __restrict__ X,
                                            const float* __restrict__ Wg,
                                            float* __restrict__ A, float* __restrict__ XW) {
    __shared__ float sM1[128][128];   // 64 KB
    __shared__ float sdct[16][128];   // 8 KB
    const int tid = threadIdx.x;
    const int bid = blockIdx.x;
    if (bid < 129) {
        const int t = tid & 127;
        const int half = tid >> 7;        // 0/1 -> rows half*8..half*8+7
        const int v0 = bid * 16;
        float acc[8];
        #pragma unroll
        for (int r = 0; r < 8; ++r) acc[r] = 0.f;
        for (int kc = 0; kc < KD; kc += 128) {
            __syncthreads();
            #pragma unroll
            for (int q = 0; q < 16; ++q) {
                int f = q * 256 + tid;              // float4 index 0..4095
                int kr = f >> 5;
                int c4 = (f & 31) * 4;
                *(float4*)&sM1[kr][c4] = *(const float4*)&M1[(size_t)(kc + kr) * 128 + c4];
            }
            #pragma unroll
            for (int p = tid; p < 2048; p += 256)
                sdct[p >> 7][p & 127] = dct_val(kc + (p & 127), v0 + (p >> 7));
            __syncthreads();
            #pragma unroll 2
            for (int ki = 0; ki < 128; ++ki) {
                float m = sM1[ki][t];
                #pragma unroll
                for (int r = 0; r < 8; ++r)
                    acc[r] += sdct[half * 8 + r][ki] * m;
            }
        }
        #pragma unroll
        for (int r = 0; r < 8; ++r) {
            int v = v0 + half * 8 + r;
            if (v < NV) {
                ushort_t hi, lo; bf16split(acc[r], hi, lo);
                ushort_t* row = Abf + (size_t)(KD + v) * KTOT;
                row[t] = hi; row[128 + t] = lo;
            }
        }
    } else if (bid < 385) {
        const int g = bid - 129;
        gemm_tile((ushort_t*)&sM1[0][0], Abf, Bbf, out, (g >> 6) * 128, g & 63, tid);
    } else if (bid < 449) {
        int id = (bid - 385) * 256 + tid;  // 16384
        float R = 0.f, I = 0.f;
        #pragma unroll 8
        for (int sk = 0; sk < 32; ++sk) {
            const float* P = Pg + (size_t)sk * 65536 + id;
            R += P[0] + P[3 * 16384];
            I += P[2 * 16384] - P[1 * 16384];
        }
        float plv = sqrtf(R * R + I * I) * (1.0f / 8192.0f);
        A[id] = (plv >= 0.5f) ? 1.0f : 0.0f;
    } else {
        int id = (bid - 449) * 256 + tid;  // 8192
        int e = id >> 6, h = id & 63;
        const float* xrow = X + (size_t)e * 128;
        float s = 0.f;
        #pragma unroll 4
        for (int t = 0; t < 128; ++t) s += xrow[t] * Wg[t * 64 + h];
        XW[id] = s;
    }
}

// ========== BACK: 0..1087 GEMM r-tiles 4..20; 1088..1151 aaug ==========
__global__ __launch_bounds__(256) void k_back(const ushort_t* __restrict__ Abf, const ushort_t* __restrict__ Bbf,
                                              float* __restrict__ out,
                                              const float* __restrict__ A, const float* __restrict__ XW,
                                              const float* __restrict__ bg, const float* __restrict__ U) {
    __shared__ ushort_t SM[24576];         // 48 KB
    const int tid = threadIdx.x;
    const int bid = blockIdx.x;
    if (bid < 1088) {
        gemm_tile(SM, Abf, Bbf, out, (4 + (bid >> 6)) * 128, bid & 63, tid);
    } else {
        // ---------- fused HG + a_aug, 2-phase 32 KB LDS reuse ----------
        float* sBuf = (float*)SM;          // phase1: XW [128][64]; phase2: HGT [64][128]
        const int g = bid - 1088;
        for (int p = tid; p < 8192; p += 256) sBuf[p] = XW[p];
        __syncthreads();
        float hacc[32];
        const int r = tid & 127;
        const int half = tid >> 7;
        {
            const float* arow = A + (size_t)r * 128;
            #pragma unroll
            for (int h = 0; h < 32; ++h) hacc[h] = 0.f;
            for (int j = 0; j < 128; ++j) {
                float av = arow[j];
                #pragma unroll
                for (int h = 0; h < 32; ++h) hacc[h] += av * sBuf[j * 64 + half * 32 + h];
            }
        }
        __syncthreads();                   // all phase-1 reads done
        #pragma unroll
        for (int h = 0; h < 32; ++h)
            sBuf[(half * 32 + h) * 128 + r] = fmaxf(hacc[h] + bg[half * 32 + h], 0.f);
        __syncthreads();
        const int id = g * 256 + tid;
        const int i = id >> 7, j = id & 127;
        float dot = 0.f;
        #pragma unroll 8
        for (int h = 0; h < 64; ++h) dot += sBuf[h * 128 + i] * sBuf[h * 128 + j];
        float p = 1.f / (1.f + expf(-dot));
        float e = 0.5f * p + 0.5f * A[id];
        float gmb = -logf(-logf(U[id]));
        float arg = (logf(e) - logf(1.f - e) + gmb) * 10.0f;
        out[AAUG_OFF + id] = 1.f / (1.f + expf(-arg));
    }
}

extern "C" void kernel_launch(void* const* d_in, const int* in_sizes, int n_in,
                              void* d_out, int out_size, void* d_ws, size_t ws_size,
                              hipStream_t stream) {
    const float* z  = (const float*)d_in[0];
    const float* LF = (const float*)d_in[1];
    const float* U  = (const float*)d_in[2];
    const float* Wg = (const float*)d_in[3];
    const float* bg = (const float*)d_in[4];
    float* out = (float*)d_out;
    float* W = (float*)d_ws;

    float* AF  = W + OFF_AF;
    ushort_t* Abf = (ushort_t*)(W + OFF_ABF);
    ushort_t* Bbf = (ushort_t*)(W + OFF_BBF);
    ushort_t* Ybf = (ushort_t*)(W + OFF_YBF);
    float* Pg  = W + OFF_PG;
    float* Pm1 = W + OFF_PM1;
    float* A   = W + OFF_A;
    float* X   = W + OFF_X;
    float* XW  = W + OFF_XW;

    k_front<<<5120, 256, 0, stream>>>(LF, z, Pm1, Ybf, Bbf);
    k_m1red<<<448, 256, 0, stream>>>(Pm1, z, AF, Abf, X, Ybf, Pg);
    k_m2   <<<481, 256, 0, stream>>>(AF, Abf, Bbf, out, Pg, X, Wg, A, XW);
    k_back <<<1152, 256, 0, stream>>>(Abf, Bbf, out, A, XW, bg, U);
}

// Round 19
// 96.468 us; speedup vs baseline: 1.1836x; 1.1836x over previous
//
#include <hip/hip_runtime.h>

#define NV 2052
#define KD 512
#define RTOT 2564
#define KTOT 256
#define JTOT 8192

typedef __attribute__((ext_vector_type(8))) short short8v;
typedef __attribute__((ext_vector_type(4))) float f32x4;
typedef unsigned short ushort_t;

// ws float offsets
#define OFF_AF   0u          // fp32 M1 [512][128]
#define OFF_ABF  65536u      // bf16 A' [2688][256]  (hi|lo)
#define OFF_BBF  409600u     // bf16 B' [8192][128]  (hi only)
#define OFF_YBF  1458176u    // bf16 Y  [256][8192]
#define OFF_PG   2506752u    // fp32 Gram partials [32][4][128][128]
#define OFF_PM1  6701056u    // fp32 m1 partials [16][512][128]
#define OFF_A    7749632u
#define OFF_X    7766016u
#define OFF_XW   7782400u    // fp32 XW [128][64]

#define SREC_OFF 4194304u
#define AAUG_OFF 21004288u

#define GLOAD16(g, l) __builtin_amdgcn_global_load_lds( \
    (const __attribute__((address_space(1))) unsigned int*)(g), \
    (__attribute__((address_space(3))) unsigned int*)(l), 16, 0, 0)

__device__ __forceinline__ float dct_val(int k, int v) {
    if (k == 0) return 1.0f / sqrtf(2052.0f);
    int m = (2 * v + 1) * k;
    int r = m % 8208;                       // exact arg reduction mod 2*pi
    float ang = (float)((double)r * (3.14159265358979323846 / 4104.0));
    return sqrtf(2.0f / 2052.0f) * cosf(ang);
}

__device__ __forceinline__ void bf16split(float x, ushort_t& hi, ushort_t& lo) {
    unsigned xb = __float_as_uint(x);
    hi = (ushort_t)(xb >> 16);
    float r = x - __uint_as_float((unsigned)hi << 16);
    lo = (ushort_t)(__float_as_uint(r) >> 16);
}

__device__ __forceinline__ ushort_t bf16rn(float x) {
    unsigned xb = __float_as_uint(x);
    return (ushort_t)((xb + 0x7fffu + ((xb >> 16) & 1u)) >> 16);
}

// ---------- shared GEMM tile body: C-tile (r0, jt) ----------
__device__ __forceinline__ void gemm_tile(ushort_t* SM, const ushort_t* __restrict__ Abf,
                                          const ushort_t* __restrict__ Bbf, float* __restrict__ out,
                                          int r0, int jt, int tid) {
    const int wave = tid >> 6;
    const int lane = tid & 63;
    const int wr = wave >> 1, wc = wave & 1;
    const int l15 = lane & 15;
    const int lhi = lane >> 4;
    const int j0 = jt * 128;
    ushort_t* AlHi = SM;
    ushort_t* AlLo = SM + 8192;
    ushort_t* Bl   = SM + 16384;
    f32x4 acc[4][4];
    #pragma unroll
    for (int i = 0; i < 4; ++i)
        #pragma unroll
        for (int j = 0; j < 4; ++j)
            acc[i][j] = (f32x4){0.f, 0.f, 0.f, 0.f};
    for (int kc = 0; kc < 128; kc += 64) {
        __syncthreads();
        #pragma unroll
        for (int i = 0; i < 4; ++i) {
            int elt = (wave * 4 + i) * 64 + lane;   // 16B-chunk id 0..1023
            int m = elt >> 3;
            int sc = (elt & 7) ^ (m & 7);
            GLOAD16(Abf + (size_t)(r0 + m) * KTOT + kc + sc * 8,       &AlHi[(wave * 4 + i) * 512]);
            GLOAD16(Abf + (size_t)(r0 + m) * KTOT + 128 + kc + sc * 8, &AlLo[(wave * 4 + i) * 512]);
            GLOAD16(Bbf + (size_t)(j0 + m) * 128 + kc + sc * 8,        &Bl[(wave * 4 + i) * 512]);
        }
        asm volatile("s_waitcnt vmcnt(0)" ::: "memory");
        __syncthreads();
        #pragma unroll
        for (int kk = 0; kk < 2; ++kk) {
            short8v ah[4], al[4], bv[4];
            #pragma unroll
            for (int mi = 0; mi < 4; ++mi) {
                int m = wr * 64 + mi * 16 + l15;
                int ch = (kk * 4 + lhi) ^ (m & 7);
                ah[mi] = *(const short8v*)&AlHi[m * 64 + ch * 8];
                al[mi] = *(const short8v*)&AlLo[m * 64 + ch * 8];
            }
            #pragma unroll
            for (int ni = 0; ni < 4; ++ni) {
                int n = wc * 64 + ni * 16 + l15;
                int ch = (kk * 4 + lhi) ^ (n & 7);
                bv[ni] = *(const short8v*)&Bl[n * 64 + ch * 8];
            }
            #pragma unroll
            for (int mi = 0; mi < 4; ++mi)
                #pragma unroll
                for (int ni = 0; ni < 4; ++ni)
                    acc[mi][ni] = __builtin_amdgcn_mfma_f32_16x16x32_bf16(ah[mi], bv[ni], acc[mi][ni], 0, 0, 0);
            #pragma unroll
            for (int mi = 0; mi < 4; ++mi)
                #pragma unroll
                for (int ni = 0; ni < 4; ++ni)
                    acc[mi][ni] = __builtin_amdgcn_mfma_f32_16x16x32_bf16(al[mi], bv[ni], acc[mi][ni], 0, 0, 0);
        }
    }
    // epilogue: LDS transpose -> coalesced float4 stores (two 64-col halves)
    float* SMf = (float*)SM;
    const unsigned bb = (unsigned)jt;
    #pragma unroll
    for (int hhalf = 0; hhalf < 2; ++hhalf) {
        __syncthreads();
        if (wc == hhalf) {
            #pragma unroll
            for (int mi = 0; mi < 4; ++mi)
                #pragma unroll
                for (int ni = 0; ni < 4; ++ni)
                    #pragma unroll
                    for (int reg = 0; reg < 4; ++reg) {
                        int rl = wr * 64 + mi * 16 + lhi * 4 + reg;
                        int cl = ni * 16 + l15;
                        SMf[rl * 68 + cl] = acc[mi][ni][reg];
                    }
        }
        __syncthreads();
        int rl = tid >> 1;
        int cs = (tid & 1) * 32;
        int r = r0 + rl;
        if (r < RTOT) {
            unsigned base;
            if (r < KD) base = bb * 65536u + (unsigned)r * 128u;
            else        base = SREC_OFF + bb * 262656u + (unsigned)(r - KD) * 128u;
            base += hhalf * 64 + cs;
            const float* src = &SMf[rl * 68 + cs];
            float* dst = out + base;
            #pragma unroll
            for (int q = 0; q < 8; ++q)
                *(float4*)(dst + q * 4) = *(const float4*)(src + q * 4);
        }
    }
}

// ========== FRONT: blocks 0..1023 = m1 partials; 1024..5119 = hilbert (2 rows/blk) ==========
__global__ __launch_bounds__(256) void k_front(const float* __restrict__ LF, const float* __restrict__ z,
                                               float* __restrict__ Pm1,
                                               ushort_t* __restrict__ Ybf, ushort_t* __restrict__ Bbf) {
    __shared__ float sh[8][132];
    const int tid = threadIdx.x;
    const int bid = blockIdx.x;
    if (bid < 1024) {
        const int t = tid & 127;
        const int kk = tid >> 7;       // 0/1
        const int k0 = (bid & 63) * 8;
        const int vch = bid >> 6;
        const int v0 = vch * 128;
        const int nv = (vch == 15) ? 132 : 128;
        for (int p = tid; p < 1056; p += 256) {
            int rr = p / 132, cc = p - rr * 132;
            sh[rr][cc] = dct_val(k0 + rr, v0 + cc);
        }
        __syncthreads();
        const float* lf = LF + (size_t)v0 * 128 + t;
        float a0 = 0.f, a1 = 0.f, a2 = 0.f, a3 = 0.f;
        for (int vi = 0; vi + 2 <= nv; vi += 2) {
            float l0 = lf[vi * 128], l1 = lf[vi * 128 + 128];
            a0 += sh[kk + 0][vi] * l0; a1 += sh[kk + 2][vi] * l0;
            a2 += sh[kk + 4][vi] * l0; a3 += sh[kk + 6][vi] * l0;
            a0 += sh[kk + 0][vi + 1] * l1; a1 += sh[kk + 2][vi + 1] * l1;
            a2 += sh[kk + 4][vi + 1] * l1; a3 += sh[kk + 6][vi + 1] * l1;
        }
        float* P = Pm1 + (size_t)vch * 65536;
        P[(k0 + kk + 0) * 128 + t] = a0;
        P[(k0 + kk + 2) * 128 + t] = a1;
        P[(k0 + kk + 4) * 128 + t] = a2;
        P[(k0 + kk + 6) * 128 + t] = a3;
    } else {
        const int t = tid & 127;
        const int rr = tid >> 7;
        const int rid = (bid - 1024) * 2 + rr;   // b*128+i
        const int b = rid >> 7, i = rid & 127;
        sh[rr][t] = z[(size_t)rid * 128 + t];
        if (tid < 128) {
            float hv = 0.f;
            if (t & 1) {
                float ang = 3.14159265358979323846f * (float)t * (1.0f / 128.0f);
                hv = (cosf(ang) / sinf(ang)) * (1.0f / 64.0f);
            }
            sh[2][t] = hv;
        }
        __syncthreads();
        float acc = 0.f;
        #pragma unroll 8
        for (int q = 0; q < 64; ++q) {
            int d = 2 * q + 1;
            acc += sh[2][d] * sh[rr][(t - d) & 127];
        }
        float zv = sh[rr][t];
        float inv = rsqrtf(zv * zv + acc * acc);
        Ybf[(size_t)i * JTOT + b * 128 + t] = bf16rn(zv * inv);
        Ybf[(size_t)(128 + i) * JTOT + b * 128 + t] = bf16rn(acc * inv);
        Bbf[(size_t)rid * 128 + t] = (ushort_t)(__float_as_uint(zv) >> 16);
    }
}

// ========== M1RED: 0..255 reduce -> AF+Abf; 256..319 X; 320..447 Gram ==========
__global__ __launch_bounds__(256) void k_m1red(const float* __restrict__ Pm1, const float* __restrict__ z,
                                               float* __restrict__ AF, ushort_t* __restrict__ Abf,
                                               float* __restrict__ X,
                                               const ushort_t* __restrict__ Ybf, float* __restrict__ Pg) {
    __shared__ ushort_t SMg[16384];   // 32 KB (gram only)
    const int tid = threadIdx.x;
    const int bid = blockIdx.x;
    if (bid < 256) {
        int id = bid * 256 + tid;  // 65536
        float s = 0.f;
        #pragma unroll
        for (int p = 0; p < 16; ++p) s += Pm1[p * 65536 + id];
        AF[id] = s;
        int rid = id >> 7, t = id & 127;
        ushort_t hi, lo; bf16split(s, hi, lo);
        ushort_t* row = Abf + (size_t)rid * KTOT;
        row[t] = hi; row[128 + t] = lo;
    } else if (bid < 320) {
        int id = (bid - 256) * 256 + tid;  // 16384
        float s0 = 0.f, s1 = 0.f, s2 = 0.f, s3 = 0.f;
        #pragma unroll 4
        for (int b = 0; b < 64; b += 4) {
            s0 += z[(size_t)(b + 0) * 16384 + id];
            s1 += z[(size_t)(b + 1) * 16384 + id];
            s2 += z[(size_t)(b + 2) * 16384 + id];
            s3 += z[(size_t)(b + 3) * 16384 + id];
        }
        X[id] = ((s0 + s1) + (s2 + s3)) * (1.0f / 64.0f);
    } else {
        // ---------- Gram partials: 128 blocks = 32 K-chunks x 4 quadrants ----------
        const int g = bid - 320;
        const int j0 = (g & 1) * 128;
        const int i0 = ((g >> 1) & 1) * 128;
        const int sk = g >> 2;               // 0..31
        const int kc0 = sk * 256;
        const int wave = tid >> 6;
        const int lane = tid & 63;
        const int wr = wave >> 1, wc = wave & 1;
        const int l15 = lane & 15;
        const int lhi = lane >> 4;
        ushort_t* Al = SMg;
        ushort_t* Bl = SMg + 8192;
        f32x4 acc[4][4];
        #pragma unroll
        for (int i = 0; i < 4; ++i)
            #pragma unroll
            for (int j = 0; j < 4; ++j)
                acc[i][j] = (f32x4){0.f, 0.f, 0.f, 0.f};
        for (int kc = kc0; kc < kc0 + 256; kc += 64) {
            __syncthreads();
            #pragma unroll
            for (int i = 0; i < 4; ++i) {
                int elt = (wave * 4 + i) * 64 + lane;
                int m = elt >> 3;
                int sc = (elt & 7) ^ (m & 7);
                GLOAD16(Ybf + (size_t)(i0 + m) * JTOT + kc + sc * 8, &Al[(wave * 4 + i) * 512]);
                GLOAD16(Ybf + (size_t)(j0 + m) * JTOT + kc + sc * 8, &Bl[(wave * 4 + i) * 512]);
            }
            asm volatile("s_waitcnt vmcnt(0)" ::: "memory");
            __syncthreads();
            #pragma unroll
            for (int kk = 0; kk < 2; ++kk) {
                short8v av[4], bv[4];
                #pragma unroll
                for (int mi = 0; mi < 4; ++mi) {
                    int m = wr * 64 + mi * 16 + l15;
                    int ch = (kk * 4 + lhi) ^ (m & 7);
                    av[mi] = *(const short8v*)&Al[m * 64 + ch * 8];
                }
                #pragma unroll
                for (int ni = 0; ni < 4; ++ni) {
                    int n = wc * 64 + ni * 16 + l15;
                    int ch = (kk * 4 + lhi) ^ (n & 7);
                    bv[ni] = *(const short8v*)&Bl[n * 64 + ch * 8];
                }
                #pragma unroll
                for (int mi = 0; mi < 4; ++mi)
                    #pragma unroll
                    for (int ni = 0; ni < 4; ++ni)
                        acc[mi][ni] = __builtin_amdgcn_mfma_f32_16x16x32_bf16(av[mi], bv[ni], acc[mi][ni], 0, 0, 0);
            }
        }
        const int q = ((g >> 1) & 1) * 2 + (g & 1);
        float* P = Pg + (size_t)(sk * 4 + q) * 16384;
        #pragma unroll
        for (int mi = 0; mi < 4; ++mi)
            #pragma unroll
            for (int reg = 0; reg < 4; ++reg) {
                int rl = wr * 64 + mi * 16 + lhi * 4 + reg;
                #pragma unroll
                for (int ni = 0; ni < 4; ++ni) {
                    int cl = wc * 64 + ni * 16 + l15;
                    P[rl * 128 + cl] = acc[mi][ni][reg];
                }
            }
    }
}

// ========== M2+: 0..256 M2 (8v/blk); 257..512 GEMM r0..3; 513..576 plv; 577..608 XW ==========
__global__ __launch_bounds__(256) void k_m2(const float* __restrict__ M1, ushort_t* __restrict__ Abf,
                                            const ushort_t* __restrict__ Bbf, float* __restrict__ out,
                                            const float* __restrict__ Pg, const float* __restrict__ X,
                                            const float* __restrict__ Wg,
                                            float* __restrict__ A, float* __restrict__ XW) {
    __shared__ float sM1[128][128];   // 64 KB
    __shared__ float sdct[8][128];    // 4 KB
    const int tid = threadIdx.x;
    const int bid = blockIdx.x;
    if (bid < 257) {
        const int t = tid & 127;
        const int half = tid >> 7;        // 0/1
        const int v0 = bid * 8;
        float acc0 = 0.f, acc1 = 0.f, acc2 = 0.f, acc3 = 0.f;
        for (int kc = 0; kc < KD; kc += 128) {
            __syncthreads();
            #pragma unroll
            for (int q = 0; q < 16; ++q) {
                int f = q * 256 + tid;              // float4 index 0..4095
                int kr = f >> 5;
                int c4 = (f & 31) * 4;
                *(float4*)&sM1[kr][c4] = *(const float4*)&M1[(size_t)(kc + kr) * 128 + c4];
            }
            #pragma unroll
            for (int p = tid; p < 1024; p += 256)
                sdct[p >> 7][p & 127] = dct_val(kc + (p & 127), v0 + (p >> 7));
            __syncthreads();
            const float* d0 = &sdct[half * 4 + 0][0];
            const float* d1 = &sdct[half * 4 + 1][0];
            const float* d2 = &sdct[half * 4 + 2][0];
            const float* d3 = &sdct[half * 4 + 3][0];
            #pragma unroll 4
            for (int ki = 0; ki < 128; ++ki) {
                float m = sM1[ki][t];
                acc0 += d0[ki] * m;
                acc1 += d1[ki] * m;
                acc2 += d2[ki] * m;
                acc3 += d3[ki] * m;
            }
        }
        float vals[4] = {acc0, acc1, acc2, acc3};
        #pragma unroll
        for (int r = 0; r < 4; ++r) {
            int v = v0 + half * 4 + r;
            if (v < NV) {
                ushort_t hi, lo; bf16split(vals[r], hi, lo);
                ushort_t* row = Abf + (size_t)(KD + v) * KTOT;
                row[t] = hi; row[128 + t] = lo;
            }
        }
    } else if (bid < 513) {
        const int g = bid - 257;
        gemm_tile((ushort_t*)&sM1[0][0], Abf, Bbf, out, (g >> 6) * 128, g & 63, tid);
    } else if (bid < 577) {
        int id = (bid - 513) * 256 + tid;  // 16384
        float R = 0.f, I = 0.f;
        #pragma unroll 8
        for (int sk = 0; sk < 32; ++sk) {
            const float* P = Pg + (size_t)sk * 65536 + id;
            R += P[0] + P[3 * 16384];
            I += P[2 * 16384] - P[1 * 16384];
        }
        float plv = sqrtf(R * R + I * I) * (1.0f / 8192.0f);
        A[id] = (plv >= 0.5f) ? 1.0f : 0.0f;
    } else {
        int id = (bid - 577) * 256 + tid;  // 8192
        int e = id >> 6, h = id & 63;
        const float* xrow = X + (size_t)e * 128;
        float s = 0.f;
        #pragma unroll 4
        for (int t = 0; t < 128; ++t) s += xrow[t] * Wg[t * 64 + h];
        XW[id] = s;
    }
}

// ========== BACK: 0..1087 GEMM r-tiles 4..20; 1088..1151 aaug ==========
__global__ __launch_bounds__(256) void k_back(const ushort_t* __restrict__ Abf, const ushort_t* __restrict__ Bbf,
                                              float* __restrict__ out,
                                              const float* __restrict__ A, const float* __restrict__ XW,
                                              const float* __restrict__ bg, const float* __restrict__ U) {
    __shared__ ushort_t SM[24576];         // 48 KB
    const int tid = threadIdx.x;
    const int bid = blockIdx.x;
    if (bid < 1088) {
        gemm_tile(SM, Abf, Bbf, out, (4 + (bid >> 6)) * 128, bid & 63, tid);
    } else {
        // ---------- fused HG + a_aug, 2-phase 32 KB LDS reuse ----------
        float* sBuf = (float*)SM;          // phase1: XW [128][64]; phase2: HGT [64][128]
        const int g = bid - 1088;
        for (int p = tid; p < 8192; p += 256) sBuf[p] = XW[p];
        __syncthreads();
        float hacc[32];
        const int r = tid & 127;
        const int half = tid >> 7;
        {
            const float* arow = A + (size_t)r * 128;
            #pragma unroll
            for (int h = 0; h < 32; ++h) hacc[h] = 0.f;
            for (int j = 0; j < 128; ++j) {
                float av = arow[j];
                #pragma unroll
                for (int h = 0; h < 32; ++h) hacc[h] += av * sBuf[j * 64 + half * 32 + h];
            }
        }
        __syncthreads();                   // all phase-1 reads done
        #pragma unroll
        for (int h = 0; h < 32; ++h)
            sBuf[(half * 32 + h) * 128 + r] = fmaxf(hacc[h] + bg[half * 32 + h], 0.f);
        __syncthreads();
        const int id = g * 256 + tid;
        const int i = id >> 7, j = id & 127;
        float dot = 0.f;
        #pragma unroll 8
        for (int h = 0; h < 64; ++h) dot += sBuf[h * 128 + i] * sBuf[h * 128 + j];
        float p = 1.f / (1.f + expf(-dot));
        float e = 0.5f * p + 0.5f * A[id];
        float gmb = -logf(-logf(U[id]));
        float arg = (logf(e) - logf(1.f - e) + gmb) * 10.0f;
        out[AAUG_OFF + id] = 1.f / (1.f + expf(-arg));
    }
}

extern "C" void kernel_launch(void* const* d_in, const int* in_sizes, int n_in,
                              void* d_out, int out_size, void* d_ws, size_t ws_size,
                              hipStream_t stream) {
    const float* z  = (const float*)d_in[0];
    const float* LF = (const float*)d_in[1];
    const float* U  = (const float*)d_in[2];
    const float* Wg = (const float*)d_in[3];
    const float* bg = (const float*)d_in[4];
    float* out = (float*)d_out;
    float* W = (float*)d_ws;

    float* AF  = W + OFF_AF;
    ushort_t* Abf = (ushort_t*)(W + OFF_ABF);
    ushort_t* Bbf = (ushort_t*)(W + OFF_BBF);
    ushort_t* Ybf = (ushort_t*)(W + OFF_YBF);
    float* Pg  = W + OFF_PG;
    float* Pm1 = W + OFF_PM1;
    float* A   = W + OFF_A;
    float* X   = W + OFF_X;
    float* XW  = W + OFF_XW;

    k_front<<<5120, 256, 0, stream>>>(LF, z, Pm1, Ybf, Bbf);
    k_m1red<<<448, 256, 0, stream>>>(Pm1, z, AF, Abf, X, Ybf, Pg);
    k_m2   <<<609, 256, 0, stream>>>(AF, Abf, Bbf, out, Pg, X, Wg, A, XW);
    k_back <<<1152, 256, 0, stream>>>(Abf, Bbf, out, A, XW, bg, U);
}

// Round 20
// 95.459 us; speedup vs baseline: 1.1961x; 1.0106x over previous
//
#include <hip/hip_runtime.h>

#define NV 2052
#define KD 512
#define RTOT 2564
#define KTOT 256
#define JTOT 8192

typedef __attribute__((ext_vector_type(8))) short short8v;
typedef __attribute__((ext_vector_type(4))) float f32x4;
typedef unsigned short ushort_t;

// ws float offsets
#define OFF_AF   0u          // fp32 M1 [512][128]
#define OFF_ABF  65536u      // bf16 A' [2688][256]  (hi|lo)
#define OFF_BBF  409600u     // bf16 B' [8192][128]  (hi only)
#define OFF_YBF  1458176u    // bf16 Y  [256][8192]
#define OFF_PG   2506752u    // fp32 Gram partials [32][4][128][128]
#define OFF_PM1  6701056u    // fp32 m1 partials [16][512][128]
#define OFF_A    7749632u
#define OFF_X    7766016u
#define OFF_XW   7782400u    // fp32 XW [128][64]

#define SREC_OFF 4194304u
#define AAUG_OFF 21004288u

#define GLOAD16(g, l) __builtin_amdgcn_global_load_lds( \
    (const __attribute__((address_space(1))) unsigned int*)(g), \
    (__attribute__((address_space(3))) unsigned int*)(l), 16, 0, 0)

__device__ __forceinline__ float dct_val(int k, int v) {
    if (k == 0) return 1.0f / sqrtf(2052.0f);
    int m = (2 * v + 1) * k;
    int r = m % 8208;                       // exact arg reduction mod 2*pi
    float ang = (float)((double)r * (3.14159265358979323846 / 4104.0));
    return sqrtf(2.0f / 2052.0f) * cosf(ang);
}

__device__ __forceinline__ void bf16split(float x, ushort_t& hi, ushort_t& lo) {
    unsigned xb = __float_as_uint(x);
    hi = (ushort_t)(xb >> 16);
    float r = x - __uint_as_float((unsigned)hi << 16);
    lo = (ushort_t)(__float_as_uint(r) >> 16);
}

__device__ __forceinline__ ushort_t bf16rn(float x) {
    unsigned xb = __float_as_uint(x);
    return (ushort_t)((xb + 0x7fffu + ((xb >> 16) & 1u)) >> 16);
}

// ---------- shared GEMM tile body: C-tile (r0, jt) ----------
__device__ __forceinline__ void gemm_tile(ushort_t* SM, const ushort_t* __restrict__ Abf,
                                          const ushort_t* __restrict__ Bbf, float* __restrict__ out,
                                          int r0, int jt, int tid) {
    const int wave = tid >> 6;
    const int lane = tid & 63;
    const int wr = wave >> 1, wc = wave & 1;
    const int l15 = lane & 15;
    const int lhi = lane >> 4;
    const int j0 = jt * 128;
    ushort_t* AlHi = SM;
    ushort_t* AlLo = SM + 8192;
    ushort_t* Bl   = SM + 16384;
    f32x4 acc[4][4];
    #pragma unroll
    for (int i = 0; i < 4; ++i)
        #pragma unroll
        for (int j = 0; j < 4; ++j)
            acc[i][j] = (f32x4){0.f, 0.f, 0.f, 0.f};
    for (int kc = 0; kc < 128; kc += 64) {
        __syncthreads();
        #pragma unroll
        for (int i = 0; i < 4; ++i) {
            int elt = (wave * 4 + i) * 64 + lane;   // 16B-chunk id 0..1023
            int m = elt >> 3;
            int sc = (elt & 7) ^ (m & 7);
            GLOAD16(Abf + (size_t)(r0 + m) * KTOT + kc + sc * 8,       &AlHi[(wave * 4 + i) * 512]);
            GLOAD16(Abf + (size_t)(r0 + m) * KTOT + 128 + kc + sc * 8, &AlLo[(wave * 4 + i) * 512]);
            GLOAD16(Bbf + (size_t)(j0 + m) * 128 + kc + sc * 8,        &Bl[(wave * 4 + i) * 512]);
        }
        asm volatile("s_waitcnt vmcnt(0)" ::: "memory");
        __syncthreads();
        #pragma unroll
        for (int kk = 0; kk < 2; ++kk) {
            short8v ah[4], al[4], bv[4];
            #pragma unroll
            for (int mi = 0; mi < 4; ++mi) {
                int m = wr * 64 + mi * 16 + l15;
                int ch = (kk * 4 + lhi) ^ (m & 7);
                ah[mi] = *(const short8v*)&AlHi[m * 64 + ch * 8];
                al[mi] = *(const short8v*)&AlLo[m * 64 + ch * 8];
            }
            #pragma unroll
            for (int ni = 0; ni < 4; ++ni) {
                int n = wc * 64 + ni * 16 + l15;
                int ch = (kk * 4 + lhi) ^ (n & 7);
                bv[ni] = *(const short8v*)&Bl[n * 64 + ch * 8];
            }
            #pragma unroll
            for (int mi = 0; mi < 4; ++mi)
                #pragma unroll
                for (int ni = 0; ni < 4; ++ni)
                    acc[mi][ni] = __builtin_amdgcn_mfma_f32_16x16x32_bf16(ah[mi], bv[ni], acc[mi][ni], 0, 0, 0);
            #pragma unroll
            for (int mi = 0; mi < 4; ++mi)
                #pragma unroll
                for (int ni = 0; ni < 4; ++ni)
                    acc[mi][ni] = __builtin_amdgcn_mfma_f32_16x16x32_bf16(al[mi], bv[ni], acc[mi][ni], 0, 0, 0);
        }
    }
    // epilogue: LDS transpose -> coalesced float4 stores (two 64-col halves)
    float* SMf = (float*)SM;
    const unsigned bb = (unsigned)jt;
    #pragma unroll
    for (int hhalf = 0; hhalf < 2; ++hhalf) {
        __syncthreads();
        if (wc == hhalf) {
            #pragma unroll
            for (int mi = 0; mi < 4; ++mi)
                #pragma unroll
                for (int ni = 0; ni < 4; ++ni)
                    #pragma unroll
                    for (int reg = 0; reg < 4; ++reg) {
                        int rl = wr * 64 + mi * 16 + lhi * 4 + reg;
                        int cl = ni * 16 + l15;
                        SMf[rl * 68 + cl] = acc[mi][ni][reg];
                    }
        }
        __syncthreads();
        int rl = tid >> 1;
        int cs = (tid & 1) * 32;
        int r = r0 + rl;
        if (r < RTOT) {
            unsigned base;
            if (r < KD) base = bb * 65536u + (unsigned)r * 128u;
            else        base = SREC_OFF + bb * 262656u + (unsigned)(r - KD) * 128u;
            base += hhalf * 64 + cs;
            const float* src = &SMf[rl * 68 + cs];
            float* dst = out + base;
            #pragma unroll
            for (int q = 0; q < 8; ++q)
                *(float4*)(dst + q * 4) = *(const float4*)(src + q * 4);
        }
    }
}

// ========== FRONT: blocks 0..1023 = m1 partials; 1024..3071 = hilbert (4 rows/blk) ==========
__global__ __launch_bounds__(256) void k_front(const float* __restrict__ LF, const float* __restrict__ z,
                                               float* __restrict__ Pm1,
                                               ushort_t* __restrict__ Ybf, ushort_t* __restrict__ Bbf) {
    __shared__ float sh[8][132];
    const int tid = threadIdx.x;
    const int bid = blockIdx.x;
    if (bid < 1024) {
        const int t = tid & 127;
        const int kk = tid >> 7;       // 0/1
        const int k0 = (bid & 63) * 8;
        const int vch = bid >> 6;
        const int v0 = vch * 128;
        const int nv = (vch == 15) ? 132 : 128;
        for (int p = tid; p < 1056; p += 256) {
            int rr = p / 132, cc = p - rr * 132;
            sh[rr][cc] = dct_val(k0 + rr, v0 + cc);
        }
        __syncthreads();
        const float* lf = LF + (size_t)v0 * 128 + t;
        float a0 = 0.f, a1 = 0.f, a2 = 0.f, a3 = 0.f;
        for (int vi = 0; vi + 2 <= nv; vi += 2) {
            float l0 = lf[vi * 128], l1 = lf[vi * 128 + 128];
            a0 += sh[kk + 0][vi] * l0; a1 += sh[kk + 2][vi] * l0;
            a2 += sh[kk + 4][vi] * l0; a3 += sh[kk + 6][vi] * l0;
            a0 += sh[kk + 0][vi + 1] * l1; a1 += sh[kk + 2][vi + 1] * l1;
            a2 += sh[kk + 4][vi + 1] * l1; a3 += sh[kk + 6][vi + 1] * l1;
        }
        float* P = Pm1 + (size_t)vch * 65536;
        P[(k0 + kk + 0) * 128 + t] = a0;
        P[(k0 + kk + 2) * 128 + t] = a1;
        P[(k0 + kk + 4) * 128 + t] = a2;
        P[(k0 + kk + 6) * 128 + t] = a3;
    } else {
        // ---- Hilbert: 4 rows per block; thread handles (row=tid>>6, t and t+64) ----
        float* zr = &sh[0][0];          // 4 rows x 128
        float* h  = &sh[4][0];          // 128 entries
        const int rr = tid >> 6;        // 0..3
        const int tb = tid & 63;
        const int rid = (bid - 1024) * 4 + rr;   // b*128+i
        const int b = rid >> 7, i = rid & 127;
        const float* zrow = z + (size_t)rid * 128;
        zr[rr * 128 + tb] = zrow[tb];
        zr[rr * 128 + tb + 64] = zrow[tb + 64];
        if (tid < 128) {
            float hv = 0.f;
            if (tid & 1) {
                float ang = 3.14159265358979323846f * (float)tid * (1.0f / 128.0f);
                hv = (cosf(ang) / sinf(ang)) * (1.0f / 64.0f);
            }
            h[tid] = hv;
        }
        __syncthreads();
        float acc0 = 0.f, acc1 = 0.f;
        #pragma unroll 8
        for (int q = 0; q < 64; ++q) {
            int d = 2 * q + 1;
            float hv = h[d];
            acc0 += hv * zr[rr * 128 + ((tb - d) & 127)];
            acc1 += hv * zr[rr * 128 + ((tb + 64 - d) & 127)];
        }
        float zv0 = zr[rr * 128 + tb];
        float zv1 = zr[rr * 128 + tb + 64];
        float inv0 = rsqrtf(zv0 * zv0 + acc0 * acc0);
        float inv1 = rsqrtf(zv1 * zv1 + acc1 * acc1);
        ushort_t* yb = Ybf + (size_t)i * JTOT + b * 128;
        yb[tb]      = bf16rn(zv0 * inv0);
        yb[tb + 64] = bf16rn(zv1 * inv1);
        ushort_t* ys = Ybf + (size_t)(128 + i) * JTOT + b * 128;
        ys[tb]      = bf16rn(acc0 * inv0);
        ys[tb + 64] = bf16rn(acc1 * inv1);
        ushort_t* row = Bbf + (size_t)rid * 128;
        row[tb]      = (ushort_t)(__float_as_uint(zv0) >> 16);
        row[tb + 64] = (ushort_t)(__float_as_uint(zv1) >> 16);
    }
}

// ========== M1RED: 0..255 reduce -> AF+Abf; 256..319 X; 320..447 Gram ==========
__global__ __launch_bounds__(256) void k_m1red(const float* __restrict__ Pm1, const float* __restrict__ z,
                                               float* __restrict__ AF, ushort_t* __restrict__ Abf,
                                               float* __restrict__ X,
                                               const ushort_t* __restrict__ Ybf, float* __restrict__ Pg) {
    __shared__ ushort_t SMg[16384];   // 32 KB (gram only)
    const int tid = threadIdx.x;
    const int bid = blockIdx.x;
    if (bid < 256) {
        int id = bid * 256 + tid;  // 65536
        float s = 0.f;
        #pragma unroll
        for (int p = 0; p < 16; ++p) s += Pm1[p * 65536 + id];
        AF[id] = s;
        int rid = id >> 7, t = id & 127;
        ushort_t hi, lo; bf16split(s, hi, lo);
        ushort_t* row = Abf + (size_t)rid * KTOT;
        row[t] = hi; row[128 + t] = lo;
    } else if (bid < 320) {
        int id = (bid - 256) * 256 + tid;  // 16384
        float s0 = 0.f, s1 = 0.f, s2 = 0.f, s3 = 0.f;
        #pragma unroll 4
        for (int b = 0; b < 64; b += 4) {
            s0 += z[(size_t)(b + 0) * 16384 + id];
            s1 += z[(size_t)(b + 1) * 16384 + id];
            s2 += z[(size_t)(b + 2) * 16384 + id];
            s3 += z[(size_t)(b + 3) * 16384 + id];
        }
        X[id] = ((s0 + s1) + (s2 + s3)) * (1.0f / 64.0f);
    } else {
        // ---------- Gram partials: 128 blocks = 32 K-chunks x 4 quadrants ----------
        const int g = bid - 320;
        const int j0 = (g & 1) * 128;
        const int i0 = ((g >> 1) & 1) * 128;
        const int sk = g >> 2;               // 0..31
        const int kc0 = sk * 256;
        const int wave = tid >> 6;
        const int lane = tid & 63;
        const int wr = wave >> 1, wc = wave & 1;
        const int l15 = lane & 15;
        const int lhi = lane >> 4;
        ushort_t* Al = SMg;
        ushort_t* Bl = SMg + 8192;
        f32x4 acc[4][4];
        #pragma unroll
        for (int i = 0; i < 4; ++i)
            #pragma unroll
            for (int j = 0; j < 4; ++j)
                acc[i][j] = (f32x4){0.f, 0.f, 0.f, 0.f};
        for (int kc = kc0; kc < kc0 + 256; kc += 64) {
            __syncthreads();
            #pragma unroll
            for (int i = 0; i < 4; ++i) {
                int elt = (wave * 4 + i) * 64 + lane;
                int m = elt >> 3;
                int sc = (elt & 7) ^ (m & 7);
                GLOAD16(Ybf + (size_t)(i0 + m) * JTOT + kc + sc * 8, &Al[(wave * 4 + i) * 512]);
                GLOAD16(Ybf + (size_t)(j0 + m) * JTOT + kc + sc * 8, &Bl[(wave * 4 + i) * 512]);
            }
            asm volatile("s_waitcnt vmcnt(0)" ::: "memory");
            __syncthreads();
            #pragma unroll
            for (int kk = 0; kk < 2; ++kk) {
                short8v av[4], bv[4];
                #pragma unroll
                for (int mi = 0; mi < 4; ++mi) {
                    int m = wr * 64 + mi * 16 + l15;
                    int ch = (kk * 4 + lhi) ^ (m & 7);
                    av[mi] = *(const short8v*)&Al[m * 64 + ch * 8];
                }
                #pragma unroll
                for (int ni = 0; ni < 4; ++ni) {
                    int n = wc * 64 + ni * 16 + l15;
                    int ch = (kk * 4 + lhi) ^ (n & 7);
                    bv[ni] = *(const short8v*)&Bl[n * 64 + ch * 8];
                }
                #pragma unroll
                for (int mi = 0; mi < 4; ++mi)
                    #pragma unroll
                    for (int ni = 0; ni < 4; ++ni)
                        acc[mi][ni] = __builtin_amdgcn_mfma_f32_16x16x32_bf16(av[mi], bv[ni], acc[mi][ni], 0, 0, 0);
            }
        }
        const int q = ((g >> 1) & 1) * 2 + (g & 1);
        float* P = Pg + (size_t)(sk * 4 + q) * 16384;
        #pragma unroll
        for (int mi = 0; mi < 4; ++mi)
            #pragma unroll
            for (int reg = 0; reg < 4; ++reg) {
                int rl = wr * 64 + mi * 16 + lhi * 4 + reg;
                #pragma unroll
                for (int ni = 0; ni < 4; ++ni) {
                    int cl = wc * 64 + ni * 16 + l15;
                    P[rl * 128 + cl] = acc[mi][ni][reg];
                }
            }
    }
}

// ========== M2+: 0..256 M2 (8v/blk); 257..512 GEMM r0..3; 513..576 plv; 577..608 XW ==========
__global__ __launch_bounds__(256) void k_m2(const float* __restrict__ M1, ushort_t* __restrict__ Abf,
                                            const ushort_t* __restrict__ Bbf, float* __restrict__ out,
                                            const float* __restrict__ Pg, const float* __restrict__ X,
                                            const float* __restrict__ Wg,
                                            float* __restrict__ A, float* __restrict__ XW) {
    __shared__ float sM1[128][128];   // 64 KB
    __shared__ float sdct[8][128];    // 4 KB
    const int tid = threadIdx.x;
    const int bid = blockIdx.x;
    if (bid < 257) {
        const int t = tid & 127;
        const int half = tid >> 7;        // 0/1
        const int v0 = bid * 8;
        float acc0 = 0.f, acc1 = 0.f, acc2 = 0.f, acc3 = 0.f;
        for (int kc = 0; kc < KD; kc += 128) {
            __syncthreads();
            #pragma unroll
            for (int q = 0; q < 16; ++q) {
                int f = q * 256 + tid;              // float4 index 0..4095
                int kr = f >> 5;
                int c4 = (f & 31) * 4;
                *(float4*)&sM1[kr][c4] = *(const float4*)&M1[(size_t)(kc + kr) * 128 + c4];
            }
            #pragma unroll
            for (int p = tid; p < 1024; p += 256)
                sdct[p >> 7][p & 127] = dct_val(kc + (p & 127), v0 + (p >> 7));
            __syncthreads();
            const float* d0 = &sdct[half * 4 + 0][0];
            const float* d1 = &sdct[half * 4 + 1][0];
            const float* d2 = &sdct[half * 4 + 2][0];
            const float* d3 = &sdct[half * 4 + 3][0];
            #pragma unroll 4
            for (int ki = 0; ki < 128; ++ki) {
                float m = sM1[ki][t];
                acc0 += d0[ki] * m;
                acc1 += d1[ki] * m;
                acc2 += d2[ki] * m;
                acc3 += d3[ki] * m;
            }
        }
        float vals[4] = {acc0, acc1, acc2, acc3};
        #pragma unroll
        for (int r = 0; r < 4; ++r) {
            int v = v0 + half * 4 + r;
            if (v < NV) {
                ushort_t hi, lo; bf16split(vals[r], hi, lo);
                ushort_t* row = Abf + (size_t)(KD + v) * KTOT;
                row[t] = hi; row[128 + t] = lo;
            }
        }
    } else if (bid < 513) {
        const int g = bid - 257;
        gemm_tile((ushort_t*)&sM1[0][0], Abf, Bbf, out, (g >> 6) * 128, g & 63, tid);
    } else if (bid < 577) {
        int id = (bid - 513) * 256 + tid;  // 16384
        float R = 0.f, I = 0.f;
        #pragma unroll 8
        for (int sk = 0; sk < 32; ++sk) {
            const float* P = Pg + (size_t)sk * 65536 + id;
            R += P[0] + P[3 * 16384];
            I += P[2 * 16384] - P[1 * 16384];
        }
        float plv = sqrtf(R * R + I * I) * (1.0f / 8192.0f);
        A[id] = (plv >= 0.5f) ? 1.0f : 0.0f;
    } else {
        int id = (bid - 577) * 256 + tid;  // 8192
        int e = id >> 6, h = id & 63;
        const float* xrow = X + (size_t)e * 128;
        float s = 0.f;
        #pragma unroll 4
        for (int t = 0; t < 128; ++t) s += xrow[t] * Wg[t * 64 + h];
        XW[id] = s;
    }
}

// ========== BACK: 0..1087 GEMM r-tiles 4..20; 1088..1151 aaug ==========
__global__ __launch_bounds__(256) void k_back(const ushort_t* __restrict__ Abf, const ushort_t* __restrict__ Bbf,
                                              float* __restrict__ out,
                                              const float* __restrict__ A, const float* __restrict__ XW,
                                              const float* __restrict__ bg, const float* __restrict__ U) {
    __shared__ ushort_t SM[24576];         // 48 KB
    const int tid = threadIdx.x;
    const int bid = blockIdx.x;
    if (bid < 1088) {
        gemm_tile(SM, Abf, Bbf, out, (4 + (bid >> 6)) * 128, bid & 63, tid);
    } else {
        // ---------- fused HG + a_aug, 2-phase 32 KB LDS reuse ----------
        float* sBuf = (float*)SM;          // phase1: XW [128][64]; phase2: HGT [64][128]
        const int g = bid - 1088;
        for (int p = tid; p < 8192; p += 256) sBuf[p] = XW[p];
        __syncthreads();
        float hacc[32];
        const int r = tid & 127;
        const int half = tid >> 7;
        {
            const float* arow = A + (size_t)r * 128;
            #pragma unroll
            for (int h = 0; h < 32; ++h) hacc[h] = 0.f;
            for (int j = 0; j < 128; ++j) {
                float av = arow[j];
                #pragma unroll
                for (int h = 0; h < 32; ++h) hacc[h] += av * sBuf[j * 64 + half * 32 + h];
            }
        }
        __syncthreads();                   // all phase-1 reads done
        #pragma unroll
        for (int h = 0; h < 32; ++h)
            sBuf[(half * 32 + h) * 128 + r] = fmaxf(hacc[h] + bg[half * 32 + h], 0.f);
        __syncthreads();
        const int id = g * 256 + tid;
        const int i = id >> 7, j = id & 127;
        float dot = 0.f;
        #pragma unroll 8
        for (int h = 0; h < 64; ++h) dot += sBuf[h * 128 + i] * sBuf[h * 128 + j];
        float p = 1.f / (1.f + expf(-dot));
        float e = 0.5f * p + 0.5f * A[id];
        float gmb = -logf(-logf(U[id]));
        float arg = (logf(e) - logf(1.f - e) + gmb) * 10.0f;
        out[AAUG_OFF + id] = 1.f / (1.f + expf(-arg));
    }
}

extern "C" void kernel_launch(void* const* d_in, const int* in_sizes, int n_in,
                              void* d_out, int out_size, void* d_ws, size_t ws_size,
                              hipStream_t stream) {
    const float* z  = (const float*)d_in[0];
    const float* LF = (const float*)d_in[1];
    const float* U  = (const float*)d_in[2];
    const float* Wg = (const float*)d_in[3];
    const float* bg = (const float*)d_in[4];
    float* out = (float*)d_out;
    float* W = (float*)d_ws;

    float* AF  = W + OFF_AF;
    ushort_t* Abf = (ushort_t*)(W + OFF_ABF);
    ushort_t* Bbf = (ushort_t*)(W + OFF_BBF);
    ushort_t* Ybf = (ushort_t*)(W + OFF_YBF);
    float* Pg  = W + OFF_PG;
    float* Pm1 = W + OFF_PM1;
    float* A   = W + OFF_A;
    float* X   = W + OFF_X;
    float* XW  = W + OFF_XW;

    k_front<<<3072, 256, 0, stream>>>(LF, z, Pm1, Ybf, Bbf);
    k_m1red<<<448, 256, 0, stream>>>(Pm1, z, AF, Abf, X, Ybf, Pg);
    k_m2   <<<609, 256, 0, stream>>>(AF, Abf, Bbf, out, Pg, X, Wg, A, XW);
    k_back <<<1152, 256, 0, stream>>>(Abf, Bbf, out, A, XW, bg, U);
}